// Round 12
// baseline (614.634 us; speedup 1.0000x reference)
//
#include <hip/hip_runtime.h>
#include <hip/hip_bf16.h>

// GPR-GNN forward on MI355X.
// R12: feature-chunked propagation v2. p stored as two 6.4MB chunk-major slabs
// ([c][N][32] uints = 64 feats); gridDim.y = chunk. Halves the random-gather
// working set (L2 hit ~31% -> ~62%) while keeping R5's proven 16-edge in-flight
// batches (unlike R3's failed 16-feat variant). Chunks are fully independent
// within a hop -> dispatch order is locality-only, never correctness.

#define NFEAT 128
#define HID   256
#define NCLS  40
#define KHOPS 10

typedef __attribute__((ext_vector_type(8))) short short8;
typedef __attribute__((ext_vector_type(4))) float floatx4;

__device__ __forceinline__ float blo(unsigned g) { return __uint_as_float(g << 16); }
__device__ __forceinline__ float bhi(unsigned g) { return __uint_as_float(g & 0xffff0000u); }
__device__ __forceinline__ unsigned f2bf(float x) {          // RNE bf16 -> low 16
  unsigned u = __float_as_uint(x);
  return (u + 0x7fffu + ((u >> 16) & 1u)) >> 16;
}
__device__ __forceinline__ unsigned bpack(float a, float b) {
  return f2bf(a) | (f2bf(b) << 16);
}

// ---- storage probe: int64 values < 2^31 have all-zero odd 32-bit words ----
__global__ void k_detect64(const unsigned int* __restrict__ raw, int* __restrict__ flag) {
  __shared__ int any;
  int t = threadIdx.x;
  if (t == 0) any = 0;
  __syncthreads();
  if (raw[2 * t + 1] != 0u) any = 1;
  __syncthreads();
  if (t == 0) flag[0] = (any == 0) ? 1 : 0;   // 1 => int64 storage
}

__global__ void k_zero(int* __restrict__ p, int n) {
  int i = blockIdx.x * blockDim.x + threadIdx.x;
  if (i < n) p[i] = 0;
}

// 1 edge/thread; stores the atomic's return as this edge's rank within dst.
__global__ void k_count(const int* __restrict__ ei32, const long long* __restrict__ ei64,
                        int E, int N, int* __restrict__ cnt, int* __restrict__ rank,
                        const int* __restrict__ flag) {
  int e = blockIdx.x * blockDim.x + threadIdx.x;
  if (e >= E) return;
  int dst = flag[0] ? (int)ei64[(size_t)E + e] : ei32[(size_t)E + e];
  if ((unsigned)dst < (unsigned)N) rank[e] = atomicAdd(&cnt[dst], 1);
  else rank[e] = -1;
}

// ---- 3-level parallel exclusive scan (tiles of 1024) ----
__global__ __launch_bounds__(256) void k_scan_a(
    const int* __restrict__ cnt, int* __restrict__ bsum, int n) {
  int t = threadIdx.x;
  int base = blockIdx.x * 1024 + t * 4;
  int s = 0;
  if (base + 3 < n) {
    int4 v = *(const int4*)(cnt + base);
    s = v.x + v.y + v.z + v.w;
  } else {
    #pragma unroll
    for (int j = 0; j < 4; ++j) if (base + j < n) s += cnt[base + j];
  }
  #pragma unroll
  for (int off = 1; off < 64; off <<= 1) s += __shfl_xor(s, off);
  __shared__ int ws[4];
  if ((t & 63) == 0) ws[t >> 6] = s;
  __syncthreads();
  if (t == 0) bsum[blockIdx.x] = ws[0] + ws[1] + ws[2] + ws[3];
}

__global__ void k_scan_mid(int* __restrict__ bsum, int* __restrict__ S,
                           int ntiles, int n) {
  int t = threadIdx.x;
  int lane = t & 63, wid = t >> 6;
  int v = (t < ntiles) ? bsum[t] : 0;
  int x = v;
  #pragma unroll
  for (int off = 1; off < 64; off <<= 1) {
    int u = __shfl_up(x, off);
    if (lane >= off) x += u;
  }
  __shared__ int ws[16];
  if (lane == 63) ws[wid] = x;
  __syncthreads();
  if (wid == 0) {
    int s2 = (lane < 16) ? ws[lane] : 0;
    #pragma unroll
    for (int off = 1; off < 16; off <<= 1) {
      int u = __shfl_up(s2, off);
      if (lane >= off) s2 += u;
    }
    if (lane < 16) ws[lane] = s2;
  }
  __syncthreads();
  int woff = wid ? ws[wid - 1] : 0;
  if (t < ntiles) bsum[t] = x - v + woff;   // exclusive tile offsets
  if (t == 0) S[n] = ws[15];                // grand total sentinel
}

// per-tile scan + apply; also emits dinv (counts are in registers here)
__global__ __launch_bounds__(256) void k_scan_c(
    const int* __restrict__ cnt, const int* __restrict__ bsum,
    int* __restrict__ S, float* __restrict__ dinv, int n) {
  int t = threadIdx.x;
  int base = blockIdx.x * 1024 + t * 4;
  int v[4];
  if (base + 3 < n) {
    int4 q = *(const int4*)(cnt + base);
    v[0] = q.x; v[1] = q.y; v[2] = q.z; v[3] = q.w;
  } else {
    #pragma unroll
    for (int j = 0; j < 4; ++j) v[j] = (base + j < n) ? cnt[base + j] : 0;
  }
  int tsum = v[0] + v[1] + v[2] + v[3];
  int lane = t & 63, wv = t >> 6;
  int x = tsum;
  #pragma unroll
  for (int off = 1; off < 64; off <<= 1) {
    int u = __shfl_up(x, off);
    if (lane >= off) x += u;
  }
  __shared__ int ws[4];
  if (lane == 63) ws[wv] = x;
  __syncthreads();
  int woff = 0;
  #pragma unroll
  for (int j = 0; j < 4; ++j) if (j < wv) woff += ws[j];
  int run = x - tsum + woff + bsum[blockIdx.x];
  #pragma unroll
  for (int j = 0; j < 4; ++j) {
    int idx = base + j;
    if (idx < n) {
      S[idx] = run;
      dinv[idx] = rsqrtf((float)(v[j] + 1));
      run += v[j];
    }
  }
}

// atomic-free fill: position = S[dst] + rank[e]; store src only.
__global__ void k_fill(const int* __restrict__ ei32, const long long* __restrict__ ei64,
                       int E, int N, const int* __restrict__ S,
                       const int* __restrict__ rank, int* __restrict__ csr,
                       const int* __restrict__ flag) {
  int e = blockIdx.x * blockDim.x + threadIdx.x;
  if (e >= E) return;
  int r = rank[e];
  if (r < 0) return;
  int src, dst;
  if (flag[0]) { src = (int)ei64[e]; dst = (int)ei64[(size_t)E + e]; }
  else         { src = ei32[e];      dst = ei32[(size_t)E + e]; }
  if ((unsigned)src >= (unsigned)N) return;
  csr[S[dst] + r] = src;
}

// fused init: p0 = dinv*x into chunk-major slabs [c][N][32]; hidden = temp[0]*x
__global__ void k_init(const float* __restrict__ x, const float* __restrict__ temp,
                       const float* __restrict__ dinv,
                       unsigned* __restrict__ h2, float* __restrict__ hidden,
                       int N) {
  int i = blockIdx.x * blockDim.x + threadIdx.x;
  if (i >= N * 64) return;
  float2 xv = ((const float2*)x)[i];
  int node = i >> 6, f2 = i & 63;
  int c = f2 >> 5, r = f2 & 31;
  float di = dinv[node];
  h2[((size_t)c * N + node) * 32 + r] = bpack(di * xv.x, di * xv.y);
  float t0 = temp[0];
  ((float2*)hidden)[i] = make_float2(t0 * xv.x, t0 * xv.y);
}

// One wave per (node, chunk); blockIdx.y = chunk c (64 feats, 6.4MB slab).
// lane = e*8+g: 8 edges per dwordx4 instr, 16 edges (2 instrs) in flight.
// Buffers hold p = dinv*h (weights telescope); h_new = dinv*(sum + p_self).
// mode 0: store p_new chunk-major + RMW f32 hidden cols [c*64, c*64+64).
// mode 1: store final bf16 hidden into row-major hid [node][64] at c*32.
__global__ __launch_bounds__(256) void k_prop(
    const unsigned* __restrict__ h2, unsigned* __restrict__ hnew2,
    float* __restrict__ hidden,
    const int* __restrict__ S, const int* __restrict__ csr,
    const float* __restrict__ dinv, const float* __restrict__ temp,
    int k, int N, int mode) {
  int wid = __builtin_amdgcn_readfirstlane(threadIdx.x >> 6);
  int lane = threadIdx.x & 63;
  int node = blockIdx.x * 4 + wid;           // uniform (SGPR) per wave
  if (node >= N) return;
  int c = blockIdx.y;
  const unsigned* hc = h2 + (size_t)c * N * 32;
  int g = lane & 7;                          // 16B sub-row: uints g*4..g*4+3
  int e = lane >> 3;                         // edge subgroup 0..7
  int s = S[node], en = S[node + 1];
  float acc[8] = {0.f, 0.f, 0.f, 0.f, 0.f, 0.f, 0.f, 0.f};
  for (int p = s; p < en; p += 16) {
    uint4 gd[2];
    float wt[2];
    #pragma unroll
    for (int t = 0; t < 2; ++t) {
      int pj = p + t * 8 + e;
      int sidx = csr[pj < en ? pj : s];      // clamped tail: redundant row, w=0
      wt[t] = (pj < en) ? 1.f : 0.f;
      gd[t] = *(const uint4*)(hc + (size_t)sidx * 32 + g * 4);
    }
    #pragma unroll
    for (int t = 0; t < 2; ++t) {
      const unsigned* gu = (const unsigned*)&gd[t];
      #pragma unroll
      for (int u = 0; u < 4; ++u) {
        acc[u * 2]     += wt[t] * blo(gu[u]);
        acc[u * 2 + 1] += wt[t] * bhi(gu[u]);
      }
    }
  }
  #pragma unroll
  for (int u = 0; u < 8; ++u) {              // reduce over the 8 edge subgroups
    acc[u] += __shfl_xor(acc[u], 8);
    acc[u] += __shfl_xor(acc[u], 16);
    acc[u] += __shfl_xor(acc[u], 32);
  }
  if (e == 0) {                              // lanes 0-7 own the epilogue
    float di = dinv[node];
    uint4 gs = *(const uint4*)(hc + (size_t)node * 32 + g * 4);
    const unsigned* su = (const unsigned*)&gs;
    #pragma unroll
    for (int u = 0; u < 4; ++u) {
      acc[u * 2]     += blo(su[u]);          // self term: p[i], weight 1
      acc[u * 2 + 1] += bhi(su[u]);
    }
    float hn[8];
    #pragma unroll
    for (int u = 0; u < 8; ++u) hn[u] = di * acc[u];   // h_new = dinv * sum
    float tk = temp[k + 1];
    float4* hp = (float4*)(hidden + (size_t)node * NFEAT + c * 64 + g * 8);
    float4 h0 = hp[0], h1 = hp[1];
    h0.x += tk * hn[0];  h0.y += tk * hn[1];
    h0.z += tk * hn[2];  h0.w += tk * hn[3];
    h1.x += tk * hn[4];  h1.y += tk * hn[5];
    h1.z += tk * hn[6];  h1.w += tk * hn[7];
    uint4 pk;
    if (mode == 0) {
      pk.x = bpack(di * hn[0], di * hn[1]);  // p_new = dinv * h_new
      pk.y = bpack(di * hn[2], di * hn[3]);
      pk.z = bpack(di * hn[4], di * hn[5]);
      pk.w = bpack(di * hn[6], di * hn[7]);
      *(uint4*)(hnew2 + ((size_t)c * N + node) * 32 + g * 4) = pk;
      hp[0] = h0;  hp[1] = h1;
    } else {
      pk.x = bpack(h0.x, h0.y);  pk.y = bpack(h0.z, h0.w);
      pk.z = bpack(h1.x, h1.y);  pk.w = bpack(h1.z, h1.w);
      // final hidden: row-major [node][64] for gemm1
      *(uint4*)(hnew2 + (size_t)node * 64 + c * 32 + g * 4) = pk;
    }
  }
}

// hidden_bf16 (Mx128) @ W1 (128x256 f32) + b1, relu -> z1 (Mx256 bf16).
__global__ __launch_bounds__(256) void k_gemm1(
    const unsigned short* __restrict__ Ab, const float* __restrict__ W1,
    const float* __restrict__ b1, unsigned short* __restrict__ z1, int M) {
  __shared__ unsigned short As[64][136];    // m-major, k contig, +8 pad
  __shared__ unsigned short Bs[16][128][8]; // [k>>3][n][k&7]: frag = ds_read_b128
  int tid = threadIdx.x;
  int m0 = blockIdx.x * 64;
  int n0 = blockIdx.y * 128;
  for (int idx = tid; idx < 64 * 16; idx += 256) {
    int m = idx >> 4, c = idx & 15;
    int row = m0 + m; if (row >= M) row = M - 1;
    uint4 v = *(const uint4*)(Ab + (size_t)row * NFEAT + c * 8);
    *(uint4*)&As[m][c * 8] = v;
  }
  for (int idx = tid; idx < 128 * 128; idx += 256) {
    int k = idx >> 7, n = idx & 127;
    Bs[k >> 3][n][k & 7] = (unsigned short)f2bf(W1[(size_t)k * HID + n0 + n]);
  }
  __syncthreads();
  int lane = tid & 63;
  int q = lane >> 4, r16 = lane & 15;
  int nw = (tid >> 6) * 32;
  floatx4 acc[4][2] = {};
  #pragma unroll
  for (int step = 0; step < 4; ++step) {
    int k0 = step * 32;
    short8 a[4], b[2];
    #pragma unroll
    for (int i = 0; i < 4; ++i)
      a[i] = *(const short8*)&As[i * 16 + r16][k0 + q * 8];
    #pragma unroll
    for (int j = 0; j < 2; ++j)
      b[j] = *(const short8*)&Bs[step * 4 + q][nw + j * 16 + r16][0];
    #pragma unroll
    for (int i = 0; i < 4; ++i)
      #pragma unroll
      for (int j = 0; j < 2; ++j)
        acc[i][j] = __builtin_amdgcn_mfma_f32_16x16x32_bf16(a[i], b[j], acc[i][j], 0, 0, 0);
  }
  __syncthreads();
  unsigned short* Zs = &As[0][0];
  #pragma unroll
  for (int j = 0; j < 2; ++j) {
    int n = nw + j * 16 + r16;
    float bias = b1[n0 + n];
    #pragma unroll
    for (int i = 0; i < 4; ++i) {
      #pragma unroll
      for (int r = 0; r < 4; ++r) {
        int m = i * 16 + q * 4 + r;
        float v = fmaxf(acc[i][j][r] + bias, 0.f);
        Zs[m * 136 + n] = (unsigned short)f2bf(v);
      }
    }
  }
  __syncthreads();
  for (int idx = tid; idx < 64 * 16; idx += 256) {
    int m = idx >> 4, c = idx & 15;
    int row = m0 + m;
    if (row < M) {
      uint4 v = *(const uint4*)&Zs[m * 136 + c * 8];
      *(uint4*)(z1 + (size_t)row * HID + n0 + c * 8) = v;
    }
  }
}

// W2 (256x40 f32) -> W2t bf16 [48][256] (n-major, k-contig; n>=40 zero-padded)
__global__ void k_w2prep(const float* __restrict__ W2, unsigned short* __restrict__ W2t) {
  int i = blockIdx.x * blockDim.x + threadIdx.x;
  if (i >= 48 * 256) return;
  int n = i >> 8, k = i & 255;
  W2t[n * 256 + k] = (n < NCLS) ? (unsigned short)f2bf(W2[(size_t)k * NCLS + n]) : 0;
}

// z1 (Mx256 bf16) @ W2t + b2 -> log_softmax -> out f32. LDS-free MFMA.
__global__ __launch_bounds__(256) void k_mlp2(
    const unsigned short* __restrict__ z1, const unsigned short* __restrict__ W2t,
    const float* __restrict__ b2, float* __restrict__ out, int N) {
  int tid = threadIdx.x;
  int lane = tid & 63;
  int wv = tid >> 6;
  int node0 = blockIdx.x * 64 + wv * 16;
  int q = lane >> 4, m = lane & 15;
  int arow = node0 + m; if (arow >= N) arow = N - 1;
  const unsigned short* aptr = z1 + (size_t)arow * HID + q * 8;
  const unsigned short* bptr = W2t + (size_t)m * HID + q * 8;   // + j*16*HID
  floatx4 acc[3] = {};
  #pragma unroll
  for (int step = 0; step < 8; ++step) {     // K = 8 x 32
    short8 a = *(const short8*)(aptr + step * 32);
    #pragma unroll
    for (int j = 0; j < 3; ++j) {
      short8 b = *(const short8*)(bptr + (size_t)j * 16 * HID + step * 32);
      acc[j] = __builtin_amdgcn_mfma_f32_16x16x32_bf16(a, b, acc[j], 0, 0, 0);
    }
  }
  int c = m;                                  // class within tile = col = lane&15
  bool v2 = (c < NCLS - 32);                  // c+32 < 40
  float bb0 = b2[c], bb1 = b2[c + 16];
  float bb2 = v2 ? b2[c + 32] : 0.f;
  #pragma unroll
  for (int r = 0; r < 4; ++r) {
    int node = node0 + q * 4 + r;
    float l0 = acc[0][r] + bb0;
    float l1 = acc[1][r] + bb1;
    float l2 = v2 ? (acc[2][r] + bb2) : -3.4e38f;
    float mx = fmaxf(fmaxf(l0, l1), l2);
    #pragma unroll
    for (int off = 1; off < 16; off <<= 1) mx = fmaxf(mx, __shfl_xor(mx, off));
    float sm = __expf(l0 - mx) + __expf(l1 - mx) + (v2 ? __expf(l2 - mx) : 0.f);
    #pragma unroll
    for (int off = 1; off < 16; off <<= 1) sm += __shfl_xor(sm, off);
    float lse = mx + __logf(sm);
    if (node < N) {
      float* op = out + (size_t)node * NCLS + c;
      op[0] = l0 - lse;
      op[16] = l1 - lse;
      if (v2) op[32] = l2 - lse;
    }
  }
}

extern "C" void kernel_launch(void* const* d_in, const int* in_sizes, int n_in,
                              void* d_out, int out_size, void* d_ws, size_t ws_size,
                              hipStream_t stream) {
  const float*     x    = (const float*)d_in[0];
  const int*       ei32 = (const int*)d_in[1];
  const long long* ei64 = (const long long*)d_in[1];
  const float*     temp = (const float*)d_in[2];
  const float*     W1   = (const float*)d_in[3];
  const float*     b1   = (const float*)d_in[4];
  const float*     W2   = (const float*)d_in[5];
  const float*     b2   = (const float*)d_in[6];
  float* out = (float*)d_out;

  int N = in_sizes[0] / NFEAT;   // 50000
  int E = in_sizes[1] / 2;       // 800000

  // workspace carve (~70 MB)
  char* w = (char*)d_ws;
  auto carve = [&](size_t bytes) -> void* {
    void* p = (void*)w;
    w += (bytes + 255) & ~(size_t)255;
    return p;
  };
  int*      flag      = (int*)     carve(4);
  int*      cnt       = (int*)     carve((size_t)N * 4);
  int*      S         = (int*)     carve(((size_t)N + 1) * 4);
  float*    dinv      = (float*)   carve((size_t)N * 4);
  int*      bsum      = (int*)     carve(1024 * 4);
  unsigned short* W2t = (unsigned short*)carve(48 * 256 * 2);
  int*      rank      = (int*)     carve((size_t)E * 4);
  int*      csr       = (int*)     carve((size_t)E * 4);
  unsigned* h_a       = (unsigned*)carve((size_t)N * 64 * 4);   // [2][N][32] p slabs
  unsigned* h_b       = (unsigned*)carve((size_t)N * 64 * 4);
  unsigned* hid       = (unsigned*)carve((size_t)N * 64 * 4);   // final hidden bf16
  float*    hidden32  = (float*)   carve((size_t)N * NFEAT * 4);
  unsigned short* z1  = (unsigned short*)hidden32;  // dead before gemm1 writes z1

  int ntiles = (N + 1023) / 1024;   // 49

  k_detect64<<<1, 256, 0, stream>>>((const unsigned int*)d_in[1], flag);
  k_zero<<<(N + 255) / 256, 256, 0, stream>>>(cnt, N);
  k_count<<<(E + 255) / 256, 256, 0, stream>>>(ei32, ei64, E, N, cnt, rank, flag);
  k_scan_a<<<ntiles, 256, 0, stream>>>(cnt, bsum, N);
  k_scan_mid<<<1, 1024, 0, stream>>>(bsum, S, ntiles, N);
  k_scan_c<<<ntiles, 256, 0, stream>>>(cnt, bsum, S, dinv, N);
  k_fill<<<(E + 255) / 256, 256, 0, stream>>>(ei32, ei64, E, N, S, rank, csr, flag);
  k_init<<<(N * 64 + 255) / 256, 256, 0, stream>>>(x, temp, dinv, h_a, hidden32, N);
  k_w2prep<<<48, 256, 0, stream>>>(W2, W2t);

  unsigned* hc = h_a;
  unsigned* hn = h_b;
  for (int k = 0; k < KHOPS - 1; ++k) {
    k_prop<<<dim3((N + 3) / 4, 2), 256, 0, stream>>>(
        hc, hn, hidden32, S, csr, dinv, temp, k, N, 0);
    unsigned* t2 = hc; hc = hn; hn = t2;
  }
  k_prop<<<dim3((N + 3) / 4, 2), 256, 0, stream>>>(
      hc, hid, hidden32, S, csr, dinv, temp, KHOPS - 1, N, 1);

  k_gemm1<<<dim3((N + 63) / 64, 2), 256, 0, stream>>>(
      (const unsigned short*)hid, W1, b1, z1, N);
  k_mlp2<<<(N + 63) / 64, 256, 0, stream>>>(z1, W2t, b2, out, N);
}

// Round 13
// 493.519 us; speedup vs baseline: 1.2454x; 1.2454x over previous
//
#include <hip/hip_runtime.h>
#include <hip/hip_bf16.h>

// GPR-GNN forward on MI355X.
// R13: revert R12 chunking (twice-refuted). Eliminate the f32 hidden RMW
// (51.2MB/hop = 40% of prop's HBM traffic per R12 counters) by keeping all
// 11 p-slabs (141MB of the 268MB ws) and computing
// hid = (sum_k temp[k] * p_k) / dinv in one streaming combine pass.
// Prop is the proven R11 row-major kernel minus all hidden logic.

#define NFEAT 128
#define HID   256
#define NCLS  40
#define KHOPS 10

typedef __attribute__((ext_vector_type(8))) short short8;
typedef __attribute__((ext_vector_type(4))) float floatx4;

__device__ __forceinline__ float blo(unsigned g) { return __uint_as_float(g << 16); }
__device__ __forceinline__ float bhi(unsigned g) { return __uint_as_float(g & 0xffff0000u); }
__device__ __forceinline__ unsigned f2bf(float x) {          // RNE bf16 -> low 16
  unsigned u = __float_as_uint(x);
  return (u + 0x7fffu + ((u >> 16) & 1u)) >> 16;
}
__device__ __forceinline__ unsigned bpack(float a, float b) {
  return f2bf(a) | (f2bf(b) << 16);
}

// ---- storage probe: int64 values < 2^31 have all-zero odd 32-bit words ----
__global__ void k_detect64(const unsigned int* __restrict__ raw, int* __restrict__ flag) {
  __shared__ int any;
  int t = threadIdx.x;
  if (t == 0) any = 0;
  __syncthreads();
  if (raw[2 * t + 1] != 0u) any = 1;
  __syncthreads();
  if (t == 0) flag[0] = (any == 0) ? 1 : 0;   // 1 => int64 storage
}

__global__ void k_zero(int* __restrict__ p, int n) {
  int i = blockIdx.x * blockDim.x + threadIdx.x;
  if (i < n) p[i] = 0;
}

// 1 edge/thread; stores the atomic's return as this edge's rank within dst.
__global__ void k_count(const int* __restrict__ ei32, const long long* __restrict__ ei64,
                        int E, int N, int* __restrict__ cnt, int* __restrict__ rank,
                        const int* __restrict__ flag) {
  int e = blockIdx.x * blockDim.x + threadIdx.x;
  if (e >= E) return;
  int dst = flag[0] ? (int)ei64[(size_t)E + e] : ei32[(size_t)E + e];
  if ((unsigned)dst < (unsigned)N) rank[e] = atomicAdd(&cnt[dst], 1);
  else rank[e] = -1;
}

// ---- 3-level parallel exclusive scan (tiles of 1024) ----
__global__ __launch_bounds__(256) void k_scan_a(
    const int* __restrict__ cnt, int* __restrict__ bsum, int n) {
  int t = threadIdx.x;
  int base = blockIdx.x * 1024 + t * 4;
  int s = 0;
  if (base + 3 < n) {
    int4 v = *(const int4*)(cnt + base);
    s = v.x + v.y + v.z + v.w;
  } else {
    #pragma unroll
    for (int j = 0; j < 4; ++j) if (base + j < n) s += cnt[base + j];
  }
  #pragma unroll
  for (int off = 1; off < 64; off <<= 1) s += __shfl_xor(s, off);
  __shared__ int ws[4];
  if ((t & 63) == 0) ws[t >> 6] = s;
  __syncthreads();
  if (t == 0) bsum[blockIdx.x] = ws[0] + ws[1] + ws[2] + ws[3];
}

__global__ void k_scan_mid(int* __restrict__ bsum, int* __restrict__ S,
                           int ntiles, int n) {
  int t = threadIdx.x;
  int lane = t & 63, wid = t >> 6;
  int v = (t < ntiles) ? bsum[t] : 0;
  int x = v;
  #pragma unroll
  for (int off = 1; off < 64; off <<= 1) {
    int u = __shfl_up(x, off);
    if (lane >= off) x += u;
  }
  __shared__ int ws[16];
  if (lane == 63) ws[wid] = x;
  __syncthreads();
  if (wid == 0) {
    int s2 = (lane < 16) ? ws[lane] : 0;
    #pragma unroll
    for (int off = 1; off < 16; off <<= 1) {
      int u = __shfl_up(s2, off);
      if (lane >= off) s2 += u;
    }
    if (lane < 16) ws[lane] = s2;
  }
  __syncthreads();
  int woff = wid ? ws[wid - 1] : 0;
  if (t < ntiles) bsum[t] = x - v + woff;   // exclusive tile offsets
  if (t == 0) S[n] = ws[15];                // grand total sentinel
}

// per-tile scan + apply; also emits dinv (counts are in registers here)
__global__ __launch_bounds__(256) void k_scan_c(
    const int* __restrict__ cnt, const int* __restrict__ bsum,
    int* __restrict__ S, float* __restrict__ dinv, int n) {
  int t = threadIdx.x;
  int base = blockIdx.x * 1024 + t * 4;
  int v[4];
  if (base + 3 < n) {
    int4 q = *(const int4*)(cnt + base);
    v[0] = q.x; v[1] = q.y; v[2] = q.z; v[3] = q.w;
  } else {
    #pragma unroll
    for (int j = 0; j < 4; ++j) v[j] = (base + j < n) ? cnt[base + j] : 0;
  }
  int tsum = v[0] + v[1] + v[2] + v[3];
  int lane = t & 63, wv = t >> 6;
  int x = tsum;
  #pragma unroll
  for (int off = 1; off < 64; off <<= 1) {
    int u = __shfl_up(x, off);
    if (lane >= off) x += u;
  }
  __shared__ int ws[4];
  if (lane == 63) ws[wv] = x;
  __syncthreads();
  int woff = 0;
  #pragma unroll
  for (int j = 0; j < 4; ++j) if (j < wv) woff += ws[j];
  int run = x - tsum + woff + bsum[blockIdx.x];
  #pragma unroll
  for (int j = 0; j < 4; ++j) {
    int idx = base + j;
    if (idx < n) {
      S[idx] = run;
      dinv[idx] = rsqrtf((float)(v[j] + 1));
      run += v[j];
    }
  }
}

// atomic-free fill: position = S[dst] + rank[e]; store src only.
__global__ void k_fill(const int* __restrict__ ei32, const long long* __restrict__ ei64,
                       int E, int N, const int* __restrict__ S,
                       const int* __restrict__ rank, int* __restrict__ csr,
                       const int* __restrict__ flag) {
  int e = blockIdx.x * blockDim.x + threadIdx.x;
  if (e >= E) return;
  int r = rank[e];
  if (r < 0) return;
  int src, dst;
  if (flag[0]) { src = (int)ei64[e]; dst = (int)ei64[(size_t)E + e]; }
  else         { src = ei32[e];      dst = ei32[(size_t)E + e]; }
  if ((unsigned)src >= (unsigned)N) return;
  csr[S[dst] + r] = src;
}

// init: p0 = dinv*x (bf16x2, row-major [node][64])
__global__ void k_init(const float* __restrict__ x, const float* __restrict__ dinv,
                       unsigned* __restrict__ p0, int total64) {
  int i = blockIdx.x * blockDim.x + threadIdx.x;
  if (i >= total64) return;
  float2 xv = ((const float2*)x)[i];
  float di = dinv[i >> 6];
  p0[i] = bpack(di * xv.x, di * xv.y);
}

// One wave per node. lane = e*16+g: 4 edges per dwordx4 gather instruction,
// 16 edges in flight. p buffers absorb the symmetric normalization, so the
// gather weight is 1 (tail mask only); p_new = dinv^2 * (sum + p_self).
// NO hidden access -- the hop-weighted sum is deferred to k_combine.
__global__ __launch_bounds__(256) void k_prop(
    const unsigned* __restrict__ pin, unsigned* __restrict__ pout,
    const int* __restrict__ S, const int* __restrict__ csr,
    const float* __restrict__ dinv, int N) {
  int wid = __builtin_amdgcn_readfirstlane(threadIdx.x >> 6);
  int lane = threadIdx.x & 63;
  int node = blockIdx.x * 4 + wid;           // uniform (SGPR) per wave
  if (node >= N) return;
  int g = lane & 15;                         // 16B sub-row: uints g*4..g*4+3
  int e = lane >> 4;                         // edge subgroup 0..3
  int s = S[node], en = S[node + 1];
  float acc[8] = {0.f, 0.f, 0.f, 0.f, 0.f, 0.f, 0.f, 0.f};
  for (int p = s; p < en; p += 16) {
    uint4 gd[4];
    float wt[4];
    #pragma unroll
    for (int t = 0; t < 4; ++t) {
      int pj = p + t * 4 + e;
      int sidx = csr[pj < en ? pj : s];      // clamped tail: redundant row, w=0
      wt[t] = (pj < en) ? 1.f : 0.f;
      gd[t] = *(const uint4*)(pin + (size_t)sidx * 64 + g * 4);  // 16B of row
    }
    #pragma unroll
    for (int t = 0; t < 4; ++t) {
      const unsigned* gu = (const unsigned*)&gd[t];
      #pragma unroll
      for (int u = 0; u < 4; ++u) {
        acc[u * 2]     += wt[t] * blo(gu[u]);
        acc[u * 2 + 1] += wt[t] * bhi(gu[u]);
      }
    }
  }
  #pragma unroll
  for (int u = 0; u < 8; ++u) {              // reduce over the 4 edge subgroups
    acc[u] += __shfl_xor(acc[u], 16);
    acc[u] += __shfl_xor(acc[u], 32);
  }
  if (e == 0) {                              // lanes 0-15 own the epilogue
    float di = dinv[node];
    float dd = di * di;
    uint4 gs = *(const uint4*)(pin + (size_t)node * 64 + g * 4);
    const unsigned* su = (const unsigned*)&gs;
    #pragma unroll
    for (int u = 0; u < 4; ++u) {
      acc[u * 2]     += blo(su[u]);          // self term: p[i], weight 1
      acc[u * 2 + 1] += bhi(su[u]);
    }
    uint4 pk;                                // p_new = dinv^2 * (sum + self)
    pk.x = bpack(dd * acc[0], dd * acc[1]);
    pk.y = bpack(dd * acc[2], dd * acc[3]);
    pk.z = bpack(dd * acc[4], dd * acc[5]);
    pk.w = bpack(dd * acc[6], dd * acc[7]);
    *(uint4*)(pout + (size_t)node * 64 + g * 4) = pk;
  }
}

// hid = (sum_k temp[k] * p_k) / dinv, streamed over all 11 slabs. bf16 out.
__global__ void k_combine(const unsigned* __restrict__ pbuf,
                          const float* __restrict__ temp,
                          const float* __restrict__ dinv,
                          unsigned* __restrict__ hid, int N) {
  int i = blockIdx.x * blockDim.x + threadIdx.x;
  int total = N * 64;
  if (i >= total) return;
  size_t slab = (size_t)total;
  float tL = 0.f, tH = 0.f;
  #pragma unroll
  for (int k = 0; k <= KHOPS; ++k) {         // 11 independent streaming loads
    unsigned v = pbuf[slab * k + i];
    float tk = temp[k];
    tL += tk * blo(v);
    tH += tk * bhi(v);
  }
  float inv = 1.f / dinv[i >> 6];            // h = p / dinv
  hid[i] = bpack(tL * inv, tH * inv);
}

// hidden_bf16 (Mx128) @ W1 (128x256 f32) + b1, relu -> z1 (Mx256 bf16).
__global__ __launch_bounds__(256) void k_gemm1(
    const unsigned short* __restrict__ Ab, const float* __restrict__ W1,
    const float* __restrict__ b1, unsigned short* __restrict__ z1, int M) {
  __shared__ unsigned short As[64][136];    // m-major, k contig, +8 pad
  __shared__ unsigned short Bs[16][128][8]; // [k>>3][n][k&7]: frag = ds_read_b128
  int tid = threadIdx.x;
  int m0 = blockIdx.x * 64;
  int n0 = blockIdx.y * 128;
  for (int idx = tid; idx < 64 * 16; idx += 256) {
    int m = idx >> 4, c = idx & 15;
    int row = m0 + m; if (row >= M) row = M - 1;
    uint4 v = *(const uint4*)(Ab + (size_t)row * NFEAT + c * 8);
    *(uint4*)&As[m][c * 8] = v;
  }
  for (int idx = tid; idx < 128 * 128; idx += 256) {
    int k = idx >> 7, n = idx & 127;
    Bs[k >> 3][n][k & 7] = (unsigned short)f2bf(W1[(size_t)k * HID + n0 + n]);
  }
  __syncthreads();
  int lane = tid & 63;
  int q = lane >> 4, r16 = lane & 15;
  int nw = (tid >> 6) * 32;
  floatx4 acc[4][2] = {};
  #pragma unroll
  for (int step = 0; step < 4; ++step) {
    int k0 = step * 32;
    short8 a[4], b[2];
    #pragma unroll
    for (int i = 0; i < 4; ++i)
      a[i] = *(const short8*)&As[i * 16 + r16][k0 + q * 8];
    #pragma unroll
    for (int j = 0; j < 2; ++j)
      b[j] = *(const short8*)&Bs[step * 4 + q][nw + j * 16 + r16][0];
    #pragma unroll
    for (int i = 0; i < 4; ++i)
      #pragma unroll
      for (int j = 0; j < 2; ++j)
        acc[i][j] = __builtin_amdgcn_mfma_f32_16x16x32_bf16(a[i], b[j], acc[i][j], 0, 0, 0);
  }
  __syncthreads();
  unsigned short* Zs = &As[0][0];
  #pragma unroll
  for (int j = 0; j < 2; ++j) {
    int n = nw + j * 16 + r16;
    float bias = b1[n0 + n];
    #pragma unroll
    for (int i = 0; i < 4; ++i) {
      #pragma unroll
      for (int r = 0; r < 4; ++r) {
        int m = i * 16 + q * 4 + r;
        float v = fmaxf(acc[i][j][r] + bias, 0.f);
        Zs[m * 136 + n] = (unsigned short)f2bf(v);
      }
    }
  }
  __syncthreads();
  for (int idx = tid; idx < 64 * 16; idx += 256) {
    int m = idx >> 4, c = idx & 15;
    int row = m0 + m;
    if (row < M) {
      uint4 v = *(const uint4*)&Zs[m * 136 + c * 8];
      *(uint4*)(z1 + (size_t)row * HID + n0 + c * 8) = v;
    }
  }
}

// W2 (256x40 f32) -> W2t bf16 [48][256] (n-major, k-contig; n>=40 zero-padded)
__global__ void k_w2prep(const float* __restrict__ W2, unsigned short* __restrict__ W2t) {
  int i = blockIdx.x * blockDim.x + threadIdx.x;
  if (i >= 48 * 256) return;
  int n = i >> 8, k = i & 255;
  W2t[n * 256 + k] = (n < NCLS) ? (unsigned short)f2bf(W2[(size_t)k * NCLS + n]) : 0;
}

// z1 (Mx256 bf16) @ W2t + b2 -> log_softmax -> out f32. LDS-free MFMA.
__global__ __launch_bounds__(256) void k_mlp2(
    const unsigned short* __restrict__ z1, const unsigned short* __restrict__ W2t,
    const float* __restrict__ b2, float* __restrict__ out, int N) {
  int tid = threadIdx.x;
  int lane = tid & 63;
  int wv = tid >> 6;
  int node0 = blockIdx.x * 64 + wv * 16;
  int q = lane >> 4, m = lane & 15;
  int arow = node0 + m; if (arow >= N) arow = N - 1;
  const unsigned short* aptr = z1 + (size_t)arow * HID + q * 8;
  const unsigned short* bptr = W2t + (size_t)m * HID + q * 8;   // + j*16*HID
  floatx4 acc[3] = {};
  #pragma unroll
  for (int step = 0; step < 8; ++step) {     // K = 8 x 32
    short8 a = *(const short8*)(aptr + step * 32);
    #pragma unroll
    for (int j = 0; j < 3; ++j) {
      short8 b = *(const short8*)(bptr + (size_t)j * 16 * HID + step * 32);
      acc[j] = __builtin_amdgcn_mfma_f32_16x16x32_bf16(a, b, acc[j], 0, 0, 0);
    }
  }
  int c = m;                                  // class within tile = col = lane&15
  bool v2 = (c < NCLS - 32);                  // c+32 < 40
  float bb0 = b2[c], bb1 = b2[c + 16];
  float bb2 = v2 ? b2[c + 32] : 0.f;
  #pragma unroll
  for (int r = 0; r < 4; ++r) {
    int node = node0 + q * 4 + r;
    float l0 = acc[0][r] + bb0;
    float l1 = acc[1][r] + bb1;
    float l2 = v2 ? (acc[2][r] + bb2) : -3.4e38f;
    float mx = fmaxf(fmaxf(l0, l1), l2);
    #pragma unroll
    for (int off = 1; off < 16; off <<= 1) mx = fmaxf(mx, __shfl_xor(mx, off));
    float sm = __expf(l0 - mx) + __expf(l1 - mx) + (v2 ? __expf(l2 - mx) : 0.f);
    #pragma unroll
    for (int off = 1; off < 16; off <<= 1) sm += __shfl_xor(sm, off);
    float lse = mx + __logf(sm);
    if (node < N) {
      float* op = out + (size_t)node * NCLS + c;
      op[0] = l0 - lse;
      op[16] = l1 - lse;
      if (v2) op[32] = l2 - lse;
    }
  }
}

extern "C" void kernel_launch(void* const* d_in, const int* in_sizes, int n_in,
                              void* d_out, int out_size, void* d_ws, size_t ws_size,
                              hipStream_t stream) {
  const float*     x    = (const float*)d_in[0];
  const int*       ei32 = (const int*)d_in[1];
  const long long* ei64 = (const long long*)d_in[1];
  const float*     temp = (const float*)d_in[2];
  const float*     W1   = (const float*)d_in[3];
  const float*     b1   = (const float*)d_in[4];
  const float*     W2   = (const float*)d_in[5];
  const float*     b2   = (const float*)d_in[6];
  float* out = (float*)d_out;

  int N = in_sizes[0] / NFEAT;   // 50000
  int E = in_sizes[1] / 2;       // 800000

  // workspace carve (~186 MB of the ~268 MB ws)
  char* w = (char*)d_ws;
  auto carve = [&](size_t bytes) -> void* {
    void* p = (void*)w;
    w += (bytes + 255) & ~(size_t)255;
    return p;
  };
  int*      flag      = (int*)     carve(4);
  int*      cnt       = (int*)     carve((size_t)N * 4);
  int*      S         = (int*)     carve(((size_t)N + 1) * 4);
  float*    dinv      = (float*)   carve((size_t)N * 4);
  int*      bsum      = (int*)     carve(1024 * 4);
  unsigned short* W2t = (unsigned short*)carve(48 * 256 * 2);
  int*      rank      = (int*)     carve((size_t)E * 4);
  int*      csr       = (int*)     carve((size_t)E * 4);
  unsigned* pbuf      = (unsigned*)carve((size_t)(KHOPS + 1) * N * 64 * 4); // 11 slabs
  unsigned* hid       = (unsigned*)carve((size_t)N * 64 * 4);   // final hidden bf16
  unsigned short* z1  = (unsigned short*)carve((size_t)N * HID * 2);

  int ntiles = (N + 1023) / 1024;   // 49
  size_t slab = (size_t)N * 64;

  k_detect64<<<1, 256, 0, stream>>>((const unsigned int*)d_in[1], flag);
  k_zero<<<(N + 255) / 256, 256, 0, stream>>>(cnt, N);
  k_count<<<(E + 255) / 256, 256, 0, stream>>>(ei32, ei64, E, N, cnt, rank, flag);
  k_scan_a<<<ntiles, 256, 0, stream>>>(cnt, bsum, N);
  k_scan_mid<<<1, 1024, 0, stream>>>(bsum, S, ntiles, N);
  k_scan_c<<<ntiles, 256, 0, stream>>>(cnt, bsum, S, dinv, N);
  k_fill<<<(E + 255) / 256, 256, 0, stream>>>(ei32, ei64, E, N, S, rank, csr, flag);
  k_init<<<(N * 64 + 255) / 256, 256, 0, stream>>>(x, dinv, pbuf, N * 64);
  k_w2prep<<<48, 256, 0, stream>>>(W2, W2t);

  for (int k = 0; k < KHOPS; ++k) {
    k_prop<<<(N + 3) / 4, 256, 0, stream>>>(
        pbuf + slab * k, pbuf + slab * (k + 1), S, csr, dinv, N);
  }
  k_combine<<<(N * 64 + 255) / 256, 256, 0, stream>>>(pbuf, temp, dinv, hid, N);

  k_gemm1<<<dim3((N + 63) / 64, 2), 256, 0, stream>>>(
      (const unsigned short*)hid, W1, b1, z1, N);
  k_mlp2<<<(N + 63) / 64, 256, 0, stream>>>(z1, W2t, b2, out, N);
}